// Round 1
// baseline (212.656 us; speedup 1.0000x reference)
//
#include <hip/hip_runtime.h>
#include <hip/hip_bf16.h>

// B=2, N=1024/branch, H=1024, NH=16, d=64, S=2N=2048. I/O f32; compute bf16 MFMA.
#define NB      2
#define NSEQ    1024
#define S2      2048
#define HDIM    1024
#define NHEADS  16
#define DHEAD   64
// Q is pre-scaled by 0.125*log2(e) in the QKV epilogue; attention uses exp2.
#define Q_SCALE 0.18033688011112042f

typedef unsigned short ushort_t;
typedef __attribute__((ext_vector_type(8))) short short8;   // 8 bf16 = 4 VGPR (MFMA A/B frag)
typedef __attribute__((ext_vector_type(4))) float f32x4;    // MFMA C/D frag (16x16)
typedef __attribute__((ext_vector_type(16))) float f32x16;  // MFMA C/D frag (32x32)

__device__ __forceinline__ ushort_t f2bf(float f) {
    union { float f; unsigned int u; } c; c.f = f;
    unsigned int u = c.u;
    u += 0x7FFFu + ((u >> 16) & 1u);   // RTNE
    return (ushort_t)(u >> 16);
}

__device__ __forceinline__ unsigned pack_bf16x2(float a, float b) {
    union { __hip_bfloat162 h; unsigned u; } cv;
    cv.h = __float22bfloat162_rn(float2{a, b});   // v_cvt_pk_bf16_f32 on gfx950
    return cv.u;
}

// ---------------------------------------------------------------------------
// One-shot f32 -> bf16 convert of x, x2, w_qkv, w_out into workspace.
// ---------------------------------------------------------------------------
__global__ __launch_bounds__(256) void cvt_all(
    const float* __restrict__ x, const float* __restrict__ x2,
    const float* __restrict__ wqkv, const float* __restrict__ wout,
    ushort_t* __restrict__ Xb, ushort_t* __restrict__ Wqb, ushort_t* __restrict__ Wob)
{
    int b = blockIdx.x;
    const float* s; ushort_t* d; int i;
    if (b < 2048)      { s = x;    d = Xb;            i = b * 256 + threadIdx.x; }
    else if (b < 4096) { s = x2;   d = Xb + 2097152;  i = (b - 2048) * 256 + threadIdx.x; }
    else if (b < 7168) { s = wqkv; d = Wqb;           i = (b - 4096) * 256 + threadIdx.x; }
    else               { s = wout; d = Wob;           i = (b - 7168) * 256 + threadIdx.x; }
    float4 v = ((const float4*)s)[i];
    ushort4 o; o.x = f2bf(v.x); o.y = f2bf(v.y); o.z = f2bf(v.z); o.w = f2bf(v.w);
    ((ushort4*)d)[i] = o;
}

// ---------------------------------------------------------------------------
// QKV MFMA GEMM: C[4096,3072] = Xb @ Wqb^T. 128x128 tile, BK=32, async
// global_load_lds DOUBLE-BUFFERED (one barrier per K-iter, prefetch issued
// after the barrier -> vmcnt drain free). Epilogue: Q (scaled), K -> [b,h,s,d]
// via per-wave LDS transpose -> packed 8B stores; V -> [b,h,d,s] ushort4.
// ---------------------------------------------------------------------------
__global__ __launch_bounds__(256) void qkv_gemm_mfma(
    const ushort_t* __restrict__ Xb, const ushort_t* __restrict__ Wqb,
    ushort_t* __restrict__ Qb, ushort_t* __restrict__ Kb, ushort_t* __restrict__ Vtb)
{
    __shared__ ushort_t As[2 * 128 * 32];   // 16 KB (dbuf)
    __shared__ ushort_t Bs[2 * 128 * 32];   // 16 KB
    __shared__ float    Sc[4][16 * 20];     // per-wave epilogue scratch
    const int t = threadIdx.x;
    const int lane = t & 63, quad = lane >> 4, l15 = lane & 15;
    const int w = t >> 6;
    const int wm = (w >> 1) * 64, wn = (w & 1) * 64;
    const int r0 = blockIdx.y * 128, c0 = blockIdx.x * 128;

    const int g_chunk = (lane & 3) ^ ((lane >> 3) & 3);   // lane-const global chunk
    const int srow_lo = w * 16 + (lane >> 2);             // row for issue p=0 (p adds 64)

    auto stage = [&](int k0, int buf) {
        #pragma unroll
        for (int p = 0; p < 2; ++p) {
            int row = srow_lo + p * 64;
            const ushort_t* gpA = Xb  + (size_t)(r0 + row) * HDIM + k0 + g_chunk * 8;
            const ushort_t* gpB = Wqb + (size_t)(c0 + row) * HDIM + k0 + g_chunk * 8;
            ushort_t* lpA = As + buf * 4096 + p * 2048 + w * 512;
            ushort_t* lpB = Bs + buf * 4096 + p * 2048 + w * 512;
            __builtin_amdgcn_global_load_lds(
                (const __attribute__((address_space(1))) void*)gpA,
                (__attribute__((address_space(3))) void*)lpA, 16, 0, 0);
            __builtin_amdgcn_global_load_lds(
                (const __attribute__((address_space(1))) void*)gpB,
                (__attribute__((address_space(3))) void*)lpB, 16, 0, 0);
        }
    };

    f32x4 acc[4][4];
    #pragma unroll
    for (int i = 0; i < 4; ++i)
        #pragma unroll
        for (int j = 0; j < 4; ++j) acc[i][j] = (f32x4){0.f, 0.f, 0.f, 0.f};

    stage(0, 0);
    stage(32, 1);
    __syncthreads();

    const int sw = (l15 >> 1) & 3;   // (ra>>1)&3 for frag rows
    for (int it = 0; it < 32; ++it) {
        const ushort_t* a = As + (it & 1) * 4096;
        const ushort_t* b = Bs + (it & 1) * 4096;
        short8 af[4], bf[4];
        #pragma unroll
        for (int mi = 0; mi < 4; ++mi) {
            int ra = wm + mi * 16 + l15;
            af[mi] = *(const short8*)(a + ra * 32 + ((quad ^ sw) * 8));
        }
        #pragma unroll
        for (int ni = 0; ni < 4; ++ni) {
            int rb = wn + ni * 16 + l15;
            bf[ni] = *(const short8*)(b + rb * 32 + ((quad ^ sw) * 8));
        }
        #pragma unroll
        for (int mi = 0; mi < 4; ++mi)
            #pragma unroll
            for (int ni = 0; ni < 4; ++ni)
                acc[mi][ni] = __builtin_amdgcn_mfma_f32_16x16x32_bf16(af[mi], bf[ni], acc[mi][ni], 0, 0, 0);
        __syncthreads();   // all waves done with buf (it&1); drain covers prefetch it+1
        if (it < 30) stage((it + 2) * 32, it & 1);
    }

    const int branch = r0 >> 11;
    const int bb     = (r0 & 2047) >> 10;
    const int qi     = c0 >> 10;            // 0=Q 1=K 2=V
    float* sc = &Sc[w][0];

    if (qi == 2) {
        #pragma unroll
        for (int mi = 0; mi < 4; ++mi) {
            int sbase = branch * NSEQ + (r0 & 1023) + wm + mi * 16 + quad * 4;
            #pragma unroll
            for (int ni = 0; ni < 4; ++ni) {
                int cc = (c0 & 1023) + wn + ni * 16;
                int h  = cc >> 6;
                int dd = (cc & 63) + l15;
                ushort4 pv;
                pv.x = f2bf(acc[mi][ni][0]); pv.y = f2bf(acc[mi][ni][1]);
                pv.z = f2bf(acc[mi][ni][2]); pv.w = f2bf(acc[mi][ni][3]);
                *(ushort4*)(Vtb + ((size_t)(bb * NHEADS + h) * DHEAD + dd) * S2 + sbase) = pv;
            }
        }
    } else {
        const float qsc = (qi == 0) ? Q_SCALE : 1.0f;
        ushort_t* base = (qi ? Kb : Qb);
        const int row = lane >> 2, ch = lane & 3;
        #pragma unroll
        for (int mi = 0; mi < 4; ++mi) {
            int sb = branch * NSEQ + (r0 & 1023) + wm + mi * 16;
            #pragma unroll
            for (int ni = 0; ni < 4; ++ni) {
                int cc = (c0 & 1023) + wn + ni * 16;
                int h  = cc >> 6;
                int db = cc & 63;
                #pragma unroll
                for (int reg = 0; reg < 4; ++reg)
                    sc[(quad * 4 + reg) * 20 + l15] = acc[mi][ni][reg] * qsc;
                float4 v = *(const float4*)&sc[row * 20 + ch * 4];
                uint2 pk;
                pk.x = pack_bf16x2(v.x, v.y);
                pk.y = pack_bf16x2(v.z, v.w);
                *(uint2*)(base + ((size_t)(bb * NHEADS + h) * S2 + sb + row) * DHEAD + db + ch * 4) = pk;
            }
        }
    }
}

// ---------------------------------------------------------------------------
// MFMA flash attention v6 per (b,h). Block = 128 q-rows, 4 waves x 32 rows.
// Swapped-operand 32x32x16 QK^T (C[key][q], P row lane-local) -> in-register
// softmax -> cvt_pk + v_permlane32_swap_b32 builds PV A-frags with NO LDS
// round-trip. K/V async-staged (global_load_lds dbuf, 1 barrier/tile).
// NO-MAX softmax (l = sum exp2), normalization in epilogue.
// K LDS swizzle: chunk = dc ^ (key&7)  (changed from (key>>2)&7 so that the
// 32x32 A-frag read -- 8 consecutive lanes = 8 consecutive keys -- is
// bank-conflict-free). V swizzle unchanged: chunk = kc ^ (d&7).
// ---------------------------------------------------------------------------
__global__ __launch_bounds__(256) void attn_mfma(
    const ushort_t* __restrict__ Qb, const ushort_t* __restrict__ Kb,
    const ushort_t* __restrict__ Vtb, ushort_t* __restrict__ Ob)
{
    __shared__ ushort_t Ks[2][64 * 64];   // 16 KB
    __shared__ ushort_t Vs[2][64 * 64];   // 16 KB

    const int t = threadIdx.x, lane = t & 63, w = t >> 6;
    const int l31 = lane & 31, hi = lane >> 5;
    const int bh = blockIdx.z * NHEADS + blockIdx.y;
    const int r0 = blockIdx.x * 128;
    const ushort_t* Qh  = Qb  + (size_t)bh * S2 * DHEAD;
    const ushort_t* Kh  = Kb  + (size_t)bh * S2 * DHEAD;
    const ushort_t* Vth = Vtb + (size_t)bh * DHEAD * S2;

    const int slot = lane & 7;
    const int rsub = lane >> 3;
    auto prefetch = [&](int kt_, int buf_) {
        #pragma unroll
        for (int c = 0; c < 2; ++c) {
            int row = w * 16 + c * 8 + rsub;
            int g   = slot ^ (row & 7);          // same swizzle for K (over key) and V (over d)
            const ushort_t* gpK = Kh  + (size_t)(kt_ * 64 + row) * DHEAD + g * 8;
            const ushort_t* gpV = Vth + (size_t)row * S2 + kt_ * 64 + g * 8;
            ushort_t* lpK = &Ks[buf_][w * 1024 + c * 512];
            ushort_t* lpV = &Vs[buf_][w * 1024 + c * 512];
            __builtin_amdgcn_global_load_lds(
                (const __attribute__((address_space(1))) void*)gpK,
                (__attribute__((address_space(3))) void*)lpK, 16, 0, 0);
            __builtin_amdgcn_global_load_lds(
                (const __attribute__((address_space(1))) void*)gpV,
                (__attribute__((address_space(3))) void*)lpV, 16, 0, 0);
        }
    };

    // Q fragments (B operand): aq[sd] = Q[q = r0+32w+l31][d = sd*16 + hi*8 .. +7]
    short8 aq[4];
    {
        const ushort_t* qp = Qh + (size_t)(r0 + 32 * w + l31) * DHEAD + hi * 8;
        #pragma unroll
        for (int sd = 0; sd < 4; ++sd) aq[sd] = *(const short8*)(qp + sd * 16);
    }

    // Loop-invariant swizzled LDS byte offsets. For both K (row=key, chunk over d)
    // and V (row=d, chunk over key): off = row*128B + ((s*2+hi)^(row&7))*16B.
    const int s7 = l31 & 7;
    int offA[4];
    #pragma unroll
    for (int s = 0; s < 4; ++s)
        offA[s] = (l31 * 64 + (((s * 2 + hi) ^ s7) * 8)) * 2;

    f32x16 oacc0, oacc1;
    #pragma unroll
    for (int i = 0; i < 16; ++i) { oacc0[i] = 0.f; oacc1[i] = 0.f; }
    float la0 = 0.f, la1 = 0.f, la2 = 0.f, la3 = 0.f;

    prefetch(0, 0);
    prefetch(1, 1);
    __syncthreads();

    for (int kt = 0; kt < S2 / 64; ++kt) {
        const char* kb = (const char*)&Ks[kt & 1][0];
        const char* vb = (const char*)&Vs[kt & 1][0];

        // QK^T swapped: s0 = S^T[keys 0..31][q], s1 = S^T[keys 32..63][q]
        f32x16 s0, s1;
        #pragma unroll
        for (int i = 0; i < 16; ++i) { s0[i] = 0.f; s1[i] = 0.f; }
        __builtin_amdgcn_s_setprio(1);
        #pragma unroll
        for (int sd = 0; sd < 4; ++sd) {
            short8 k0 = *(const short8*)(kb + offA[sd]);
            short8 k1 = *(const short8*)(kb + offA[sd] + 4096);
            s0 = __builtin_amdgcn_mfma_f32_32x32x16_bf16(k0, aq[sd], s0, 0, 0, 0);
            s1 = __builtin_amdgcn_mfma_f32_32x32x16_bf16(k1, aq[sd], s1, 0, 0, 0);
        }
        __builtin_amdgcn_s_setprio(0);

        // In-register softmax + P^T redistribution.
        // Reg r of s0/s1 holds key_local = (r&3) + 8*(r>>2) + 4*hi.
        // cvt_pk makes key pairs; permlane32_swap(a,c): a <- W_even (lo keeps
        // keys {k,k+1}, hi gets other half's {k+8,k+9}), c <- W_odd.
        unsigned pw[4][4];   // pw[sk][word]: A-frag words for key-step sk (16 keys)
        #pragma unroll
        for (int half = 0; half < 2; ++half) {
            float p[8], q[8];
            #pragma unroll
            for (int j = 0; j < 8; ++j) {
                p[j] = __builtin_exp2f(s0[half * 8 + j]);
                q[j] = __builtin_exp2f(s1[half * 8 + j]);
            }
            la0 += p[0] + p[4]; la1 += p[1] + p[5];
            la2 += p[2] + p[6]; la3 += p[3] + p[7];
            la0 += q[0] + q[4]; la1 += q[1] + q[5];
            la2 += q[2] + q[6]; la3 += q[3] + q[7];

            unsigned a0 = pack_bf16x2(p[0], p[1]), b0 = pack_bf16x2(p[2], p[3]);
            unsigned c0 = pack_bf16x2(p[4], p[5]), d0 = pack_bf16x2(p[6], p[7]);
            asm("v_permlane32_swap_b32 %0, %1" : "+v"(a0), "+v"(c0));
            asm("v_permlane32_swap_b32 %0, %1" : "+v"(b0), "+v"(d0));
            pw[half][0] = a0; pw[half][1] = b0; pw[half][2] = c0; pw[half][3] = d0;

            unsigned a1 = pack_bf16x2(q[0], q[1]), b1 = pack_bf16x2(q[2], q[3]);
            unsigned c1 = pack_bf16x2(q[4], q[5]), d1 = pack_bf16x2(q[6], q[7]);
            asm("v_permlane32_swap_b32 %0, %1" : "+v"(a1), "+v"(c1));
            asm("v_permlane32_swap_b32 %0, %1" : "+v"(b1), "+v"(d1));
            pw[2 + half][0] = a1; pw[2 + half][1] = b1; pw[2 + half][2] = c1; pw[2 + half][3] = d1;
        }

        // PV: O[q][d] += P[q][keys] V[keys][d], two d-tiles of 32.
        __builtin_amdgcn_s_setprio(1);
        #pragma unroll
        for (int sk = 0; sk < 4; ++sk) {
            union { unsigned u[4]; short8 s8; } pa;
            pa.u[0] = pw[sk][0]; pa.u[1] = pw[sk][1];
            pa.u[2] = pw[sk][2]; pa.u[3] = pw[sk][3];
            short8 v0 = *(const short8*)(vb + offA[sk]);
            short8 v1 = *(const short8*)(vb + offA[sk] + 4096);
            oacc0 = __builtin_amdgcn_mfma_f32_32x32x16_bf16(pa.s8, v0, oacc0, 0, 0, 0);
            oacc1 = __builtin_amdgcn_mfma_f32_32x32x16_bf16(pa.s8, v1, oacc1, 0, 0, 0);
        }
        __builtin_amdgcn_s_setprio(0);

        __syncthreads();   // all waves done with buf (kt&1); drain covers prefetch kt+1
        if (kt + 2 < S2 / 64) prefetch(kt + 2, kt & 1);
    }

    // l[q=l31]: this lane has half the keys, the opposite 32-half has the rest.
    float l = (la0 + la1) + (la2 + la3);
    l += __shfl_xor(l, 32);
    const float inv = 1.0f / l;

    ushort_t* obase = Ob + (size_t)bh * S2 * DHEAD;
    #pragma unroll
    for (int r = 0; r < 16; ++r) {
        const int ql = (r & 3) + 8 * (r >> 2) + 4 * hi;   // q row of oacc reg r
        const float iv = __shfl(inv, ql);                  // l[q] lives at lane q (both halves)
        const size_t rowoff = (size_t)(r0 + 32 * w + ql) * DHEAD;
        obase[rowoff + l31]      = f2bf(oacc0[r] * iv);
        obase[rowoff + 32 + l31] = f2bf(oacc1[r] * iv);
    }
}

// ---------------------------------------------------------------------------
// Proj MFMA GEMM: out[4096,1024] (f32) = gather(O)[4096,1024] @ Wob^T + b_out.
// BM=128 x BN=64, grid (16,32)=512 blocks. Async staging double-buffered
// (one barrier per K-iter). Epilogue: LDS transpose -> f32x4 stores.
// ---------------------------------------------------------------------------
__global__ __launch_bounds__(256) void proj_gemm_mfma(
    const ushort_t* __restrict__ Ob, const ushort_t* __restrict__ Wob,
    const float* __restrict__ Bo, float* __restrict__ Out)
{
    __shared__ ushort_t As[2 * 128 * 32];   // 16 KB
    __shared__ ushort_t Bs[2 * 64 * 32];    // 8 KB
    __shared__ float    Sc[4][16 * 20];
    const int t = threadIdx.x;
    const int lane = t & 63, quad = lane >> 4, l15 = lane & 15;
    const int w = t >> 6;
    const int wm = (w >> 1) * 64, wn = (w & 1) * 32;
    const int r0 = blockIdx.y * 128, c0 = blockIdx.x * 64;
    const int branch = r0 >> 11, bb = (r0 & 2047) >> 10;

    const int g_chunk = (lane & 3) ^ ((lane >> 3) & 3);
    const int srow_lo = w * 16 + (lane >> 2);

    auto stage = [&](int k0, int buf) {
        int h = k0 >> 6, off = k0 & 63;
        const ushort_t* gpB = Wob + (size_t)(c0 + srow_lo) * HDIM + k0 + g_chunk * 8;
        ushort_t* lpB = Bs + buf * 2048 + w * 512;
        __builtin_amdgcn_global_load_lds(
            (const __attribute__((address_space(1))) void*)gpB,
            (__attribute__((address_space(3))) void*)lpB, 16, 0, 0);
        #pragma unroll
        for (int p = 0; p < 2; ++p) {
            int row = srow_lo + p * 64;
            int s = branch * NSEQ + (r0 & 1023) + row;
            const ushort_t* gpA = Ob + ((size_t)(bb * NHEADS + h) * S2 + s) * DHEAD + off + g_chunk * 8;
            ushort_t* lpA = As + buf * 4096 + p * 2048 + w * 512;
            __builtin_amdgcn_global_load_lds(
                (const __attribute__((address_space(1))) void*)gpA,
                (__attribute__((address_space(3))) void*)lpA, 16, 0, 0);
        }
    };

    f32x4 acc[4][2];
    #pragma unroll
    for (int i = 0; i < 4; ++i)
        #pragma unroll
        for (int j = 0; j < 2; ++j) acc[i][j] = (f32x4){0.f, 0.f, 0.f, 0.f};

    stage(0, 0);
    stage(32, 1);
    __syncthreads();

    const int sw = (l15 >> 1) & 3;
    for (int it = 0; it < 32; ++it) {
        const ushort_t* a = As + (it & 1) * 4096;
        const ushort_t* b = Bs + (it & 1) * 2048;
        short8 af[4], bf[2];
        #pragma unroll
        for (int mi = 0; mi < 4; ++mi) {
            int ra = wm + mi * 16 + l15;
            af[mi] = *(const short8*)(a + ra * 32 + ((quad ^ sw) * 8));
        }
        #pragma unroll
        for (int ni = 0; ni < 2; ++ni) {
            int rb = wn + ni * 16 + l15;
            bf[ni] = *(const short8*)(b + rb * 32 + ((quad ^ sw) * 8));
        }
        #pragma unroll
        for (int mi = 0; mi < 4; ++mi)
            #pragma unroll
            for (int ni = 0; ni < 2; ++ni)
                acc[mi][ni] = __builtin_amdgcn_mfma_f32_16x16x32_bf16(af[mi], bf[ni], acc[mi][ni], 0, 0, 0);
        __syncthreads();
        if (it < 30) stage((it + 2) * 32, it & 1);
    }

    float* sc = &Sc[w][0];
    const int row = lane >> 2, ch = lane & 3;
    #pragma unroll
    for (int mi = 0; mi < 4; ++mi) {
        int rb0 = r0 + wm + mi * 16;
        #pragma unroll
        for (int ni = 0; ni < 2; ++ni) {
            int cb = c0 + wn + ni * 16;
            #pragma unroll
            for (int reg = 0; reg < 4; ++reg)
                sc[(quad * 4 + reg) * 20 + l15] = acc[mi][ni][reg];
            float4 v = *(const float4*)&sc[row * 20 + ch * 4];
            float4 bias = *(const float4*)&Bo[cb + ch * 4];
            v.x += bias.x; v.y += bias.y; v.z += bias.z; v.w += bias.w;
            *(float4*)&Out[(size_t)(rb0 + row) * HDIM + cb + ch * 4] = v;
        }
    }
}

extern "C" void kernel_launch(void* const* d_in, const int* in_sizes, int n_in,
                              void* d_out, int out_size, void* d_ws, size_t ws_size,
                              hipStream_t stream) {
    const float* x    = (const float*)d_in[0];
    const float* x2   = (const float*)d_in[1];
    const float* wqkv = (const float*)d_in[2];
    const float* wout = (const float*)d_in[3];
    const float* bout = (const float*)d_in[4];
    float* out = (float*)d_out;

    // ws layout (bytes): Xb 8M | Wqb 6M | Wob 2M | Qb 8M | Kb 8M | Vtb 8M | Ob 8M = 48 MB
    char* ws = (char*)d_ws;
    ushort_t* Xb  = (ushort_t*)(ws);
    ushort_t* Wqb = (ushort_t*)(ws + (8u  << 20));
    ushort_t* Wob = (ushort_t*)(ws + (14u << 20));
    ushort_t* Qb  = (ushort_t*)(ws + (16u << 20));
    ushort_t* Kb  = (ushort_t*)(ws + (24u << 20));
    ushort_t* Vtb = (ushort_t*)(ws + (32u << 20));
    ushort_t* Ob  = (ushort_t*)(ws + (40u << 20));

    cvt_all<<<8192, 256, 0, stream>>>(x, x2, wqkv, wout, Xb, Wqb, Wob);
    qkv_gemm_mfma<<<dim3(24, 32), 256, 0, stream>>>(Xb, Wqb, Qb, Kb, Vtb);
    attn_mfma<<<dim3(S2 / 128, NHEADS, NB), 256, 0, stream>>>(Qb, Kb, Vtb, Ob);
    proj_gemm_mfma<<<dim3(16, 32), 256, 0, stream>>>(Ob, Wob, bout, out);
}

// Round 2
// 209.761 us; speedup vs baseline: 1.0138x; 1.0138x over previous
//
#include <hip/hip_runtime.h>
#include <hip/hip_bf16.h>

// B=2, N=1024/branch, H=1024, NH=16, d=64, S=2N=2048. I/O f32; compute bf16 MFMA.
#define NB      2
#define NSEQ    1024
#define S2      2048
#define HDIM    1024
#define NHEADS  16
#define DHEAD   64
// Q is pre-scaled by 0.125*log2(e) in the QKV epilogue; attention uses exp2.
#define Q_SCALE 0.18033688011112042f

typedef unsigned short ushort_t;
typedef __attribute__((ext_vector_type(8))) short short8;   // 8 bf16 = 4 VGPR (MFMA A/B frag)
typedef __attribute__((ext_vector_type(4))) float f32x4;    // MFMA C/D frag (16x16)
typedef __attribute__((ext_vector_type(16))) float f32x16;  // MFMA C/D frag (32x32)

__device__ __forceinline__ ushort_t f2bf(float f) {
    union { float f; unsigned int u; } c; c.f = f;
    unsigned int u = c.u;
    u += 0x7FFFu + ((u >> 16) & 1u);   // RTNE
    return (ushort_t)(u >> 16);
}

__device__ __forceinline__ unsigned pack_bf16x2(float a, float b) {
    union { __hip_bfloat162 h; unsigned u; } cv;
    cv.h = __float22bfloat162_rn(float2{a, b});   // v_cvt_pk_bf16_f32 on gfx950
    return cv.u;
}

// ---------------------------------------------------------------------------
// One-shot f32 -> bf16 convert of x, x2, w_qkv, w_out into workspace.
// ---------------------------------------------------------------------------
__global__ __launch_bounds__(256) void cvt_all(
    const float* __restrict__ x, const float* __restrict__ x2,
    const float* __restrict__ wqkv, const float* __restrict__ wout,
    ushort_t* __restrict__ Xb, ushort_t* __restrict__ Wqb, ushort_t* __restrict__ Wob)
{
    int b = blockIdx.x;
    const float* s; ushort_t* d; int i;
    if (b < 2048)      { s = x;    d = Xb;            i = b * 256 + threadIdx.x; }
    else if (b < 4096) { s = x2;   d = Xb + 2097152;  i = (b - 2048) * 256 + threadIdx.x; }
    else if (b < 7168) { s = wqkv; d = Wqb;           i = (b - 4096) * 256 + threadIdx.x; }
    else               { s = wout; d = Wob;           i = (b - 7168) * 256 + threadIdx.x; }
    float4 v = ((const float4*)s)[i];
    ushort4 o; o.x = f2bf(v.x); o.y = f2bf(v.y); o.z = f2bf(v.z); o.w = f2bf(v.w);
    ((ushort4*)d)[i] = o;
}

// ---------------------------------------------------------------------------
// QKV MFMA GEMM: C[4096,3072] = Xb @ Wqb^T. 128x128 tile, BK=32, async
// global_load_lds DOUBLE-BUFFERED (one barrier per K-iter, prefetch issued
// after the barrier -> vmcnt drain free). Epilogue: Q (scaled), K -> [b,h,s,d]
// via per-wave LDS transpose -> packed 8B stores; V -> [b,h,d,s] ushort4.
// ---------------------------------------------------------------------------
__global__ __launch_bounds__(256) void qkv_gemm_mfma(
    const ushort_t* __restrict__ Xb, const ushort_t* __restrict__ Wqb,
    ushort_t* __restrict__ Qb, ushort_t* __restrict__ Kb, ushort_t* __restrict__ Vtb)
{
    __shared__ ushort_t As[2 * 128 * 32];   // 16 KB (dbuf)
    __shared__ ushort_t Bs[2 * 128 * 32];   // 16 KB
    __shared__ float    Sc[4][16 * 20];     // per-wave epilogue scratch
    const int t = threadIdx.x;
    const int lane = t & 63, quad = lane >> 4, l15 = lane & 15;
    const int w = t >> 6;
    const int wm = (w >> 1) * 64, wn = (w & 1) * 64;
    const int r0 = blockIdx.y * 128, c0 = blockIdx.x * 128;

    const int g_chunk = (lane & 3) ^ ((lane >> 3) & 3);   // lane-const global chunk
    const int srow_lo = w * 16 + (lane >> 2);             // row for issue p=0 (p adds 64)

    auto stage = [&](int k0, int buf) {
        #pragma unroll
        for (int p = 0; p < 2; ++p) {
            int row = srow_lo + p * 64;
            const ushort_t* gpA = Xb  + (size_t)(r0 + row) * HDIM + k0 + g_chunk * 8;
            const ushort_t* gpB = Wqb + (size_t)(c0 + row) * HDIM + k0 + g_chunk * 8;
            ushort_t* lpA = As + buf * 4096 + p * 2048 + w * 512;
            ushort_t* lpB = Bs + buf * 4096 + p * 2048 + w * 512;
            __builtin_amdgcn_global_load_lds(
                (const __attribute__((address_space(1))) void*)gpA,
                (__attribute__((address_space(3))) void*)lpA, 16, 0, 0);
            __builtin_amdgcn_global_load_lds(
                (const __attribute__((address_space(1))) void*)gpB,
                (__attribute__((address_space(3))) void*)lpB, 16, 0, 0);
        }
    };

    f32x4 acc[4][4];
    #pragma unroll
    for (int i = 0; i < 4; ++i)
        #pragma unroll
        for (int j = 0; j < 4; ++j) acc[i][j] = (f32x4){0.f, 0.f, 0.f, 0.f};

    stage(0, 0);
    stage(32, 1);
    __syncthreads();

    const int sw = (l15 >> 1) & 3;   // (ra>>1)&3 for frag rows
    for (int it = 0; it < 32; ++it) {
        const ushort_t* a = As + (it & 1) * 4096;
        const ushort_t* b = Bs + (it & 1) * 4096;
        short8 af[4], bf[4];
        #pragma unroll
        for (int mi = 0; mi < 4; ++mi) {
            int ra = wm + mi * 16 + l15;
            af[mi] = *(const short8*)(a + ra * 32 + ((quad ^ sw) * 8));
        }
        #pragma unroll
        for (int ni = 0; ni < 4; ++ni) {
            int rb = wn + ni * 16 + l15;
            bf[ni] = *(const short8*)(b + rb * 32 + ((quad ^ sw) * 8));
        }
        #pragma unroll
        for (int mi = 0; mi < 4; ++mi)
            #pragma unroll
            for (int ni = 0; ni < 4; ++ni)
                acc[mi][ni] = __builtin_amdgcn_mfma_f32_16x16x32_bf16(af[mi], bf[ni], acc[mi][ni], 0, 0, 0);
        __syncthreads();   // all waves done with buf (it&1); drain covers prefetch it+1
        if (it < 30) stage((it + 2) * 32, it & 1);
    }

    const int branch = r0 >> 11;
    const int bb     = (r0 & 2047) >> 10;
    const int qi     = c0 >> 10;            // 0=Q 1=K 2=V
    float* sc = &Sc[w][0];

    if (qi == 2) {
        #pragma unroll
        for (int mi = 0; mi < 4; ++mi) {
            int sbase = branch * NSEQ + (r0 & 1023) + wm + mi * 16 + quad * 4;
            #pragma unroll
            for (int ni = 0; ni < 4; ++ni) {
                int cc = (c0 & 1023) + wn + ni * 16;
                int h  = cc >> 6;
                int dd = (cc & 63) + l15;
                ushort4 pv;
                pv.x = f2bf(acc[mi][ni][0]); pv.y = f2bf(acc[mi][ni][1]);
                pv.z = f2bf(acc[mi][ni][2]); pv.w = f2bf(acc[mi][ni][3]);
                *(ushort4*)(Vtb + ((size_t)(bb * NHEADS + h) * DHEAD + dd) * S2 + sbase) = pv;
            }
        }
    } else {
        const float qsc = (qi == 0) ? Q_SCALE : 1.0f;
        ushort_t* base = (qi ? Kb : Qb);
        const int row = lane >> 2, ch = lane & 3;
        #pragma unroll
        for (int mi = 0; mi < 4; ++mi) {
            int sb = branch * NSEQ + (r0 & 1023) + wm + mi * 16;
            #pragma unroll
            for (int ni = 0; ni < 4; ++ni) {
                int cc = (c0 & 1023) + wn + ni * 16;
                int h  = cc >> 6;
                int db = cc & 63;
                #pragma unroll
                for (int reg = 0; reg < 4; ++reg)
                    sc[(quad * 4 + reg) * 20 + l15] = acc[mi][ni][reg] * qsc;
                float4 v = *(const float4*)&sc[row * 20 + ch * 4];
                uint2 pk;
                pk.x = pack_bf16x2(v.x, v.y);
                pk.y = pack_bf16x2(v.z, v.w);
                *(uint2*)(base + ((size_t)(bb * NHEADS + h) * S2 + sb + row) * DHEAD + db + ch * 4) = pk;
            }
        }
    }
}

// ---------------------------------------------------------------------------
// MFMA flash attention v7 per (b,h). Block = 128 q-rows, 4 waves x 32 rows.
// Swapped-operand 32x32x16 QK^T, in-register softmax (cvt_pk + permlane32),
// NO-MAX (l = sum exp2), normalization in epilogue.
// R2 changes vs v6 (both target the ~65% stall fraction):
//  (1) XCD swizzle: 1D grid 512, decoded so all 16 q-tiles of one (b,h)
//      land on the SAME XCD (bh === id mod 8). Per-XCD K/V working set
//      16MB -> 2MB => L2-resident, staging latency ~900 -> ~250 cyc.
//  (2) TRIPLE-buffered staging with counted vmcnt: s_waitcnt vmcnt(4)
//      (wait only the tile about to be consumed) + raw s_barrier +
//      sched_barrier(0), instead of __syncthreads' vmcnt(0) full drain.
//      Prefetch distance 2 over 3 buffers: P(kt+2) writes buf[(kt+2)%3],
//      last read at kt-1, and every wave passed barrier(kt) only after
//      finishing compute(kt-1) -> no reuse race. Last iter peeled (vmcnt 0).
// ---------------------------------------------------------------------------
__global__ __launch_bounds__(256) void attn_mfma(
    const ushort_t* __restrict__ Qb, const ushort_t* __restrict__ Kb,
    const ushort_t* __restrict__ Vtb, ushort_t* __restrict__ Ob)
{
    __shared__ ushort_t Ks[3 * 64 * 64];   // 24 KB (3-buf)
    __shared__ ushort_t Vs[3 * 64 * 64];   // 24 KB

    const int t = threadIdx.x, lane = t & 63, w = t >> 6;
    const int l31 = lane & 31, hi = lane >> 5;

    // XCD-aware decode: hw assigns XCD = dispatch_id % 8 (round-robin).
    // bh = ((j&3)<<3) | (id&7)  =>  bh % 8 == XCD, all 16 q-tiles of a bh
    // share one XCD's L2.
    const int id  = blockIdx.x;
    const int j   = id >> 3;
    const int bh  = ((j & 3) << 3) | (id & 7);   // = batch*16 + head, 0..31
    const int r0  = (j >> 2) * 128;

    const ushort_t* Qh  = Qb  + (size_t)bh * S2 * DHEAD;
    const ushort_t* Kh  = Kb  + (size_t)bh * S2 * DHEAD;
    const ushort_t* Vth = Vtb + (size_t)bh * DHEAD * S2;

    const int slot = lane & 7;
    const int rsub = lane >> 3;
    auto prefetch = [&](int kt_, int buf_) {
        #pragma unroll
        for (int c = 0; c < 2; ++c) {
            int row = w * 16 + c * 8 + rsub;
            int g   = slot ^ (row & 7);          // same swizzle for K (over key) and V (over d)
            const ushort_t* gpK = Kh  + (size_t)(kt_ * 64 + row) * DHEAD + g * 8;
            const ushort_t* gpV = Vth + (size_t)row * S2 + kt_ * 64 + g * 8;
            ushort_t* lpK = &Ks[buf_ * 4096 + w * 1024 + c * 512];
            ushort_t* lpV = &Vs[buf_ * 4096 + w * 1024 + c * 512];
            __builtin_amdgcn_global_load_lds(
                (const __attribute__((address_space(1))) void*)gpK,
                (__attribute__((address_space(3))) void*)lpK, 16, 0, 0);
            __builtin_amdgcn_global_load_lds(
                (const __attribute__((address_space(1))) void*)gpV,
                (__attribute__((address_space(3))) void*)lpV, 16, 0, 0);
        }
    };

    // Q fragments (B operand): aq[sd] = Q[q = r0+32w+l31][d = sd*16 + hi*8 .. +7]
    short8 aq[4];
    {
        const ushort_t* qp = Qh + (size_t)(r0 + 32 * w + l31) * DHEAD + hi * 8;
        #pragma unroll
        for (int sd = 0; sd < 4; ++sd) aq[sd] = *(const short8*)(qp + sd * 16);
    }

    // Loop-invariant swizzled LDS byte offsets. For both K (row=key, chunk over d)
    // and V (row=d, chunk over key): off = row*128B + ((s*2+hi)^(row&7))*16B.
    const int s7 = l31 & 7;
    int offA[4];
    #pragma unroll
    for (int s = 0; s < 4; ++s)
        offA[s] = (l31 * 64 + (((s * 2 + hi) ^ s7) * 8)) * 2;

    f32x16 oacc0, oacc1;
    #pragma unroll
    for (int i = 0; i < 16; ++i) { oacc0[i] = 0.f; oacc1[i] = 0.f; }
    float la0 = 0.f, la1 = 0.f, la2 = 0.f, la3 = 0.f;

    prefetch(0, 0);
    prefetch(1, 1);

    int bi = 0;   // buffer holding tile kt
    for (int kt = 0; kt < S2 / 64; ++kt) {
        // Wait only this tile's 4 loads (the kt+1 prefetch stays in flight);
        // raw barrier makes all waves' stage-writes visible; sched_barrier
        // pins the LDS reads below the barrier.
        if (kt < S2 / 64 - 1) asm volatile("s_waitcnt vmcnt(4)" ::: "memory");
        else                  asm volatile("s_waitcnt vmcnt(0)" ::: "memory");
        __builtin_amdgcn_s_barrier();
        __builtin_amdgcn_sched_barrier(0);

        const char* kb = (const char*)Ks + bi * 8192;
        const char* vb = (const char*)Vs + bi * 8192;

        // QK^T swapped: s0 = S^T[keys 0..31][q], s1 = S^T[keys 32..63][q]
        f32x16 s0, s1;
        #pragma unroll
        for (int i = 0; i < 16; ++i) { s0[i] = 0.f; s1[i] = 0.f; }
        __builtin_amdgcn_s_setprio(1);
        #pragma unroll
        for (int sd = 0; sd < 4; ++sd) {
            short8 k0 = *(const short8*)(kb + offA[sd]);
            short8 k1 = *(const short8*)(kb + offA[sd] + 4096);
            s0 = __builtin_amdgcn_mfma_f32_32x32x16_bf16(k0, aq[sd], s0, 0, 0, 0);
            s1 = __builtin_amdgcn_mfma_f32_32x32x16_bf16(k1, aq[sd], s1, 0, 0, 0);
        }
        __builtin_amdgcn_s_setprio(0);

        // In-register softmax + P^T redistribution.
        unsigned pw[4][4];   // pw[sk][word]: A-frag words for key-step sk (16 keys)
        #pragma unroll
        for (int half = 0; half < 2; ++half) {
            float p[8], q[8];
            #pragma unroll
            for (int jj = 0; jj < 8; ++jj) {
                p[jj] = __builtin_exp2f(s0[half * 8 + jj]);
                q[jj] = __builtin_exp2f(s1[half * 8 + jj]);
            }
            la0 += p[0] + p[4]; la1 += p[1] + p[5];
            la2 += p[2] + p[6]; la3 += p[3] + p[7];
            la0 += q[0] + q[4]; la1 += q[1] + q[5];
            la2 += q[2] + q[6]; la3 += q[3] + q[7];

            unsigned a0 = pack_bf16x2(p[0], p[1]), b0 = pack_bf16x2(p[2], p[3]);
            unsigned c0 = pack_bf16x2(p[4], p[5]), d0 = pack_bf16x2(p[6], p[7]);
            asm("v_permlane32_swap_b32 %0, %1" : "+v"(a0), "+v"(c0));
            asm("v_permlane32_swap_b32 %0, %1" : "+v"(b0), "+v"(d0));
            pw[half][0] = a0; pw[half][1] = b0; pw[half][2] = c0; pw[half][3] = d0;

            unsigned a1 = pack_bf16x2(q[0], q[1]), b1 = pack_bf16x2(q[2], q[3]);
            unsigned c1 = pack_bf16x2(q[4], q[5]), d1 = pack_bf16x2(q[6], q[7]);
            asm("v_permlane32_swap_b32 %0, %1" : "+v"(a1), "+v"(c1));
            asm("v_permlane32_swap_b32 %0, %1" : "+v"(b1), "+v"(d1));
            pw[2 + half][0] = a1; pw[2 + half][1] = b1; pw[2 + half][2] = c1; pw[2 + half][3] = d1;
        }

        // PV: O[q][d] += P[q][keys] V[keys][d], two d-tiles of 32.
        __builtin_amdgcn_s_setprio(1);
        #pragma unroll
        for (int sk = 0; sk < 4; ++sk) {
            union { unsigned u[4]; short8 s8; } pa;
            pa.u[0] = pw[sk][0]; pa.u[1] = pw[sk][1];
            pa.u[2] = pw[sk][2]; pa.u[3] = pw[sk][3];
            short8 v0 = *(const short8*)(vb + offA[sk]);
            short8 v1 = *(const short8*)(vb + offA[sk] + 4096);
            oacc0 = __builtin_amdgcn_mfma_f32_32x32x16_bf16(pa.s8, v0, oacc0, 0, 0, 0);
            oacc1 = __builtin_amdgcn_mfma_f32_32x32x16_bf16(pa.s8, v1, oacc1, 0, 0, 0);
        }
        __builtin_amdgcn_s_setprio(0);

        // Distance-2 prefetch into the third buffer (no reuse race, see header).
        if (kt + 2 < S2 / 64) {
            int pb = bi + 2; if (pb >= 3) pb -= 3;
            prefetch(kt + 2, pb);
        }
        bi = (bi == 2) ? 0 : bi + 1;
    }

    // l[q=l31]: this lane has half the keys, the opposite 32-half has the rest.
    float l = (la0 + la1) + (la2 + la3);
    l += __shfl_xor(l, 32);
    const float inv = 1.0f / l;

    ushort_t* obase = Ob + (size_t)bh * S2 * DHEAD;
    #pragma unroll
    for (int r = 0; r < 16; ++r) {
        const int ql = (r & 3) + 8 * (r >> 2) + 4 * hi;   // q row of oacc reg r
        const float iv = __shfl(inv, ql);                  // l[q] lives at lane q (both halves)
        const size_t rowoff = (size_t)(r0 + 32 * w + ql) * DHEAD;
        obase[rowoff + l31]      = f2bf(oacc0[r] * iv);
        obase[rowoff + 32 + l31] = f2bf(oacc1[r] * iv);
    }
}

// ---------------------------------------------------------------------------
// Proj MFMA GEMM: out[4096,1024] (f32) = gather(O)[4096,1024] @ Wob^T + b_out.
// BM=128 x BN=64, grid (16,32)=512 blocks. Async staging double-buffered
// (one barrier per K-iter). Epilogue: LDS transpose -> f32x4 stores.
// ---------------------------------------------------------------------------
__global__ __launch_bounds__(256) void proj_gemm_mfma(
    const ushort_t* __restrict__ Ob, const ushort_t* __restrict__ Wob,
    const float* __restrict__ Bo, float* __restrict__ Out)
{
    __shared__ ushort_t As[2 * 128 * 32];   // 16 KB
    __shared__ ushort_t Bs[2 * 64 * 32];    // 8 KB
    __shared__ float    Sc[4][16 * 20];
    const int t = threadIdx.x;
    const int lane = t & 63, quad = lane >> 4, l15 = lane & 15;
    const int w = t >> 6;
    const int wm = (w >> 1) * 64, wn = (w & 1) * 32;
    const int r0 = blockIdx.y * 128, c0 = blockIdx.x * 64;
    const int branch = r0 >> 11, bb = (r0 & 2047) >> 10;

    const int g_chunk = (lane & 3) ^ ((lane >> 3) & 3);
    const int srow_lo = w * 16 + (lane >> 2);

    auto stage = [&](int k0, int buf) {
        int h = k0 >> 6, off = k0 & 63;
        const ushort_t* gpB = Wob + (size_t)(c0 + srow_lo) * HDIM + k0 + g_chunk * 8;
        ushort_t* lpB = Bs + buf * 2048 + w * 512;
        __builtin_amdgcn_global_load_lds(
            (const __attribute__((address_space(1))) void*)gpB,
            (__attribute__((address_space(3))) void*)lpB, 16, 0, 0);
        #pragma unroll
        for (int p = 0; p < 2; ++p) {
            int row = srow_lo + p * 64;
            int s = branch * NSEQ + (r0 & 1023) + row;
            const ushort_t* gpA = Ob + ((size_t)(bb * NHEADS + h) * S2 + s) * DHEAD + off + g_chunk * 8;
            ushort_t* lpA = As + buf * 4096 + p * 2048 + w * 512;
            __builtin_amdgcn_global_load_lds(
                (const __attribute__((address_space(1))) void*)gpA,
                (__attribute__((address_space(3))) void*)lpA, 16, 0, 0);
        }
    };

    f32x4 acc[4][2];
    #pragma unroll
    for (int i = 0; i < 4; ++i)
        #pragma unroll
        for (int j = 0; j < 2; ++j) acc[i][j] = (f32x4){0.f, 0.f, 0.f, 0.f};

    stage(0, 0);
    stage(32, 1);
    __syncthreads();

    const int sw = (l15 >> 1) & 3;
    for (int it = 0; it < 32; ++it) {
        const ushort_t* a = As + (it & 1) * 4096;
        const ushort_t* b = Bs + (it & 1) * 2048;
        short8 af[4], bf[2];
        #pragma unroll
        for (int mi = 0; mi < 4; ++mi) {
            int ra = wm + mi * 16 + l15;
            af[mi] = *(const short8*)(a + ra * 32 + ((quad ^ sw) * 8));
        }
        #pragma unroll
        for (int ni = 0; ni < 2; ++ni) {
            int rb = wn + ni * 16 + l15;
            bf[ni] = *(const short8*)(b + rb * 32 + ((quad ^ sw) * 8));
        }
        #pragma unroll
        for (int mi = 0; mi < 4; ++mi)
            #pragma unroll
            for (int ni = 0; ni < 2; ++ni)
                acc[mi][ni] = __builtin_amdgcn_mfma_f32_16x16x32_bf16(af[mi], bf[ni], acc[mi][ni], 0, 0, 0);
        __syncthreads();
        if (it < 30) stage((it + 2) * 32, it & 1);
    }

    float* sc = &Sc[w][0];
    const int row = lane >> 2, ch = lane & 3;
    #pragma unroll
    for (int mi = 0; mi < 4; ++mi) {
        int rb0 = r0 + wm + mi * 16;
        #pragma unroll
        for (int ni = 0; ni < 2; ++ni) {
            int cb = c0 + wn + ni * 16;
            #pragma unroll
            for (int reg = 0; reg < 4; ++reg)
                sc[(quad * 4 + reg) * 20 + l15] = acc[mi][ni][reg];
            float4 v = *(const float4*)&sc[row * 20 + ch * 4];
            float4 bias = *(const float4*)&Bo[cb + ch * 4];
            v.x += bias.x; v.y += bias.y; v.z += bias.z; v.w += bias.w;
            *(float4*)&Out[(size_t)(rb0 + row) * HDIM + cb + ch * 4] = v;
        }
    }
}

extern "C" void kernel_launch(void* const* d_in, const int* in_sizes, int n_in,
                              void* d_out, int out_size, void* d_ws, size_t ws_size,
                              hipStream_t stream) {
    const float* x    = (const float*)d_in[0];
    const float* x2   = (const float*)d_in[1];
    const float* wqkv = (const float*)d_in[2];
    const float* wout = (const float*)d_in[3];
    const float* bout = (const float*)d_in[4];
    float* out = (float*)d_out;

    // ws layout (bytes): Xb 8M | Wqb 6M | Wob 2M | Qb 8M | Kb 8M | Vtb 8M | Ob 8M = 48 MB
    char* ws = (char*)d_ws;
    ushort_t* Xb  = (ushort_t*)(ws);
    ushort_t* Wqb = (ushort_t*)(ws + (8u  << 20));
    ushort_t* Wob = (ushort_t*)(ws + (14u << 20));
    ushort_t* Qb  = (ushort_t*)(ws + (16u << 20));
    ushort_t* Kb  = (ushort_t*)(ws + (24u << 20));
    ushort_t* Vtb = (ushort_t*)(ws + (32u << 20));
    ushort_t* Ob  = (ushort_t*)(ws + (40u << 20));

    cvt_all<<<8192, 256, 0, stream>>>(x, x2, wqkv, wout, Xb, Wqb, Wob);
    qkv_gemm_mfma<<<dim3(24, 32), 256, 0, stream>>>(Xb, Wqb, Qb, Kb, Vtb);
    attn_mfma<<<512, 256, 0, stream>>>(Qb, Kb, Vtb, Ob);
    proj_gemm_mfma<<<dim3(16, 32), 256, 0, stream>>>(Ob, Wob, bout, out);
}

// Round 3
// 205.770 us; speedup vs baseline: 1.0335x; 1.0194x over previous
//
#include <hip/hip_runtime.h>
#include <hip/hip_bf16.h>

// B=2, N=1024/branch, H=1024, NH=16, d=64, S=2N=2048. I/O f32; compute bf16 MFMA.
#define NB      2
#define NSEQ    1024
#define S2      2048
#define HDIM    1024
#define NHEADS  16
#define DHEAD   64
// Q is pre-scaled by 0.125*log2(e) in the QKV epilogue; attention uses exp2.
#define Q_SCALE 0.18033688011112042f

typedef unsigned short ushort_t;
typedef __attribute__((ext_vector_type(8))) short short8;   // 8 bf16 = 4 VGPR (MFMA A/B frag)
typedef __attribute__((ext_vector_type(4))) float f32x4;    // MFMA C/D frag (16x16)
typedef __attribute__((ext_vector_type(16))) float f32x16;  // MFMA C/D frag (32x32)

__device__ __forceinline__ ushort_t f2bf(float f) {
    union { float f; unsigned int u; } c; c.f = f;
    unsigned int u = c.u;
    u += 0x7FFFu + ((u >> 16) & 1u);   // RTNE
    return (ushort_t)(u >> 16);
}

__device__ __forceinline__ unsigned pack_bf16x2(float a, float b) {
    union { __hip_bfloat162 h; unsigned u; } cv;
    cv.h = __float22bfloat162_rn(float2{a, b});   // v_cvt_pk_bf16_f32 on gfx950
    return cv.u;
}

// ---------------------------------------------------------------------------
// One-shot f32 -> bf16 convert of x, x2, w_qkv, w_out into workspace.
// ---------------------------------------------------------------------------
__global__ __launch_bounds__(256) void cvt_all(
    const float* __restrict__ x, const float* __restrict__ x2,
    const float* __restrict__ wqkv, const float* __restrict__ wout,
    ushort_t* __restrict__ Xb, ushort_t* __restrict__ Wqb, ushort_t* __restrict__ Wob)
{
    int b = blockIdx.x;
    const float* s; ushort_t* d; int i;
    if (b < 2048)      { s = x;    d = Xb;            i = b * 256 + threadIdx.x; }
    else if (b < 4096) { s = x2;   d = Xb + 2097152;  i = (b - 2048) * 256 + threadIdx.x; }
    else if (b < 7168) { s = wqkv; d = Wqb;           i = (b - 4096) * 256 + threadIdx.x; }
    else               { s = wout; d = Wob;           i = (b - 7168) * 256 + threadIdx.x; }
    float4 v = ((const float4*)s)[i];
    ushort4 o; o.x = f2bf(v.x); o.y = f2bf(v.y); o.z = f2bf(v.z); o.w = f2bf(v.w);
    ((ushort4*)d)[i] = o;
}

// ---------------------------------------------------------------------------
// QKV MFMA GEMM: C[4096,3072] = Xb @ Wqb^T. 128x128 tile, BK=32, async
// global_load_lds DOUBLE-BUFFERED (one barrier per K-iter, prefetch issued
// after the barrier -> vmcnt drain free). Epilogue: Q (scaled), K -> [b,h,s,d]
// via per-wave LDS transpose -> packed 8B stores; V -> [b,h,d,s] ushort4.
// ---------------------------------------------------------------------------
__global__ __launch_bounds__(256) void qkv_gemm_mfma(
    const ushort_t* __restrict__ Xb, const ushort_t* __restrict__ Wqb,
    ushort_t* __restrict__ Qb, ushort_t* __restrict__ Kb, ushort_t* __restrict__ Vtb)
{
    __shared__ ushort_t As[2 * 128 * 32];   // 16 KB (dbuf)
    __shared__ ushort_t Bs[2 * 128 * 32];   // 16 KB
    __shared__ float    Sc[4][16 * 20];     // per-wave epilogue scratch
    const int t = threadIdx.x;
    const int lane = t & 63, quad = lane >> 4, l15 = lane & 15;
    const int w = t >> 6;
    const int wm = (w >> 1) * 64, wn = (w & 1) * 64;
    const int r0 = blockIdx.y * 128, c0 = blockIdx.x * 128;

    const int g_chunk = (lane & 3) ^ ((lane >> 3) & 3);   // lane-const global chunk
    const int srow_lo = w * 16 + (lane >> 2);             // row for issue p=0 (p adds 64)

    auto stage = [&](int k0, int buf) {
        #pragma unroll
        for (int p = 0; p < 2; ++p) {
            int row = srow_lo + p * 64;
            const ushort_t* gpA = Xb  + (size_t)(r0 + row) * HDIM + k0 + g_chunk * 8;
            const ushort_t* gpB = Wqb + (size_t)(c0 + row) * HDIM + k0 + g_chunk * 8;
            ushort_t* lpA = As + buf * 4096 + p * 2048 + w * 512;
            ushort_t* lpB = Bs + buf * 4096 + p * 2048 + w * 512;
            __builtin_amdgcn_global_load_lds(
                (const __attribute__((address_space(1))) void*)gpA,
                (__attribute__((address_space(3))) void*)lpA, 16, 0, 0);
            __builtin_amdgcn_global_load_lds(
                (const __attribute__((address_space(1))) void*)gpB,
                (__attribute__((address_space(3))) void*)lpB, 16, 0, 0);
        }
    };

    f32x4 acc[4][4];
    #pragma unroll
    for (int i = 0; i < 4; ++i)
        #pragma unroll
        for (int j = 0; j < 4; ++j) acc[i][j] = (f32x4){0.f, 0.f, 0.f, 0.f};

    stage(0, 0);
    stage(32, 1);
    __syncthreads();

    const int sw = (l15 >> 1) & 3;   // (ra>>1)&3 for frag rows
    for (int it = 0; it < 32; ++it) {
        const ushort_t* a = As + (it & 1) * 4096;
        const ushort_t* b = Bs + (it & 1) * 4096;
        short8 af[4], bf[4];
        #pragma unroll
        for (int mi = 0; mi < 4; ++mi) {
            int ra = wm + mi * 16 + l15;
            af[mi] = *(const short8*)(a + ra * 32 + ((quad ^ sw) * 8));
        }
        #pragma unroll
        for (int ni = 0; ni < 4; ++ni) {
            int rb = wn + ni * 16 + l15;
            bf[ni] = *(const short8*)(b + rb * 32 + ((quad ^ sw) * 8));
        }
        #pragma unroll
        for (int mi = 0; mi < 4; ++mi)
            #pragma unroll
            for (int ni = 0; ni < 4; ++ni)
                acc[mi][ni] = __builtin_amdgcn_mfma_f32_16x16x32_bf16(af[mi], bf[ni], acc[mi][ni], 0, 0, 0);
        __syncthreads();   // all waves done with buf (it&1); drain covers prefetch it+1
        if (it < 30) stage((it + 2) * 32, it & 1);
    }

    const int branch = r0 >> 11;
    const int bb     = (r0 & 2047) >> 10;
    const int qi     = c0 >> 10;            // 0=Q 1=K 2=V
    float* sc = &Sc[w][0];

    if (qi == 2) {
        #pragma unroll
        for (int mi = 0; mi < 4; ++mi) {
            int sbase = branch * NSEQ + (r0 & 1023) + wm + mi * 16 + quad * 4;
            #pragma unroll
            for (int ni = 0; ni < 4; ++ni) {
                int cc = (c0 & 1023) + wn + ni * 16;
                int h  = cc >> 6;
                int dd = (cc & 63) + l15;
                ushort4 pv;
                pv.x = f2bf(acc[mi][ni][0]); pv.y = f2bf(acc[mi][ni][1]);
                pv.z = f2bf(acc[mi][ni][2]); pv.w = f2bf(acc[mi][ni][3]);
                *(ushort4*)(Vtb + ((size_t)(bb * NHEADS + h) * DHEAD + dd) * S2 + sbase) = pv;
            }
        }
    } else {
        const float qsc = (qi == 0) ? Q_SCALE : 1.0f;
        ushort_t* base = (qi ? Kb : Qb);
        const int row = lane >> 2, ch = lane & 3;
        #pragma unroll
        for (int mi = 0; mi < 4; ++mi) {
            int sb = branch * NSEQ + (r0 & 1023) + wm + mi * 16;
            #pragma unroll
            for (int ni = 0; ni < 4; ++ni) {
                int cc = (c0 & 1023) + wn + ni * 16;
                int h  = cc >> 6;
                int db = cc & 63;
                #pragma unroll
                for (int reg = 0; reg < 4; ++reg)
                    sc[(quad * 4 + reg) * 20 + l15] = acc[mi][ni][reg] * qsc;
                float4 v = *(const float4*)&sc[row * 20 + ch * 4];
                uint2 pk;
                pk.x = pack_bf16x2(v.x, v.y);
                pk.y = pack_bf16x2(v.z, v.w);
                *(uint2*)(base + ((size_t)(bb * NHEADS + h) * S2 + sb + row) * DHEAD + db + ch * 4) = pk;
            }
        }
    }
}

// ---------------------------------------------------------------------------
// MFMA flash attention v8 per (b,h). Block = 128 q-rows, 4 waves x 32 rows.
// Swapped-operand 32x32x16 QK^T, in-register softmax (cvt_pk + permlane32),
// NO-MAX (l = sum exp2), normalization in epilogue.
// R3: 1-tile-lookahead software pipeline to break phase serialization:
//   iter kt:  QK(kt+1) [MFMA, indep]  ||  SM(kt) [VALU/trans, from scores
//   computed last iter]  ->  PV(kt) [MFMA].  Score state double-buffered in
//   REGISTERS with static names sA/sB via unroll-by-2 (no runtime indexing).
//   4 LDS buffers, stage distance 3, counted vmcnt(4) per iter:
//     - QK(kt+1) in iter kt needs stage(kt+1): guaranteed by iter kt-1's
//       vmcnt(4) (outstanding there = S(kt+1),S(kt+2); waits oldest 4).
//     - buf[kt%4] rewritten only by stage(kt+4), issued in iter kt+1 AFTER
//       the iter-kt barrier that ends all reads of tile kt. No race.
//   kt=29 uses vmcnt(0) (last stage S(31) must land for QK(31) in iter 30);
//   iters 30,31 need no sync (no more stages, all tiles visible).
// ---------------------------------------------------------------------------
__global__ __launch_bounds__(256) void attn_mfma(
    const ushort_t* __restrict__ Qb, const ushort_t* __restrict__ Kb,
    const ushort_t* __restrict__ Vtb, ushort_t* __restrict__ Ob)
{
    __shared__ ushort_t Ks[4 * 64 * 64];   // 32 KB (4-buf)
    __shared__ ushort_t Vs[4 * 64 * 64];   // 32 KB

    const int t = threadIdx.x, lane = t & 63, w = t >> 6;
    const int l31 = lane & 31, hi = lane >> 5;

    // XCD-aware decode: hw assigns XCD = dispatch_id % 8 (round-robin).
    // bh = ((j&3)<<3) | (id&7)  =>  bh % 8 == XCD, all 16 q-tiles of a bh
    // share one XCD's L2 (R2: FETCH 70->12 MB, K/V L2-resident).
    const int id  = blockIdx.x;
    const int j   = id >> 3;
    const int bh  = ((j & 3) << 3) | (id & 7);   // = batch*16 + head, 0..31
    const int r0  = (j >> 2) * 128;

    const ushort_t* Qh  = Qb  + (size_t)bh * S2 * DHEAD;
    const ushort_t* Kh  = Kb  + (size_t)bh * S2 * DHEAD;
    const ushort_t* Vth = Vtb + (size_t)bh * DHEAD * S2;

    const int slot = lane & 7;
    const int rsub = lane >> 3;
    auto prefetch = [&](int kt_, int buf_) {
        #pragma unroll
        for (int c = 0; c < 2; ++c) {
            int row = w * 16 + c * 8 + rsub;
            int g   = slot ^ (row & 7);          // same swizzle for K (over key) and V (over d)
            const ushort_t* gpK = Kh  + (size_t)(kt_ * 64 + row) * DHEAD + g * 8;
            const ushort_t* gpV = Vth + (size_t)row * S2 + kt_ * 64 + g * 8;
            ushort_t* lpK = &Ks[buf_ * 4096 + w * 1024 + c * 512];
            ushort_t* lpV = &Vs[buf_ * 4096 + w * 1024 + c * 512];
            __builtin_amdgcn_global_load_lds(
                (const __attribute__((address_space(1))) void*)gpK,
                (__attribute__((address_space(3))) void*)lpK, 16, 0, 0);
            __builtin_amdgcn_global_load_lds(
                (const __attribute__((address_space(1))) void*)gpV,
                (__attribute__((address_space(3))) void*)lpV, 16, 0, 0);
        }
    };

    // Q fragments (B operand): aq[sd] = Q[q = r0+32w+l31][d = sd*16 + hi*8 .. +7]
    short8 aq[4];
    {
        const ushort_t* qp = Qh + (size_t)(r0 + 32 * w + l31) * DHEAD + hi * 8;
        #pragma unroll
        for (int sd = 0; sd < 4; ++sd) aq[sd] = *(const short8*)(qp + sd * 16);
    }

    // Loop-invariant swizzled LDS byte offsets. For both K (row=key, chunk over d)
    // and V (row=d, chunk over key): off = row*128B + ((s*2+hi)^(row&7))*16B.
    const int s7 = l31 & 7;
    int offA[4];
    #pragma unroll
    for (int s = 0; s < 4; ++s)
        offA[s] = (l31 * 64 + (((s * 2 + hi) ^ s7) * 8)) * 2;

    f32x16 oacc0, oacc1;
    #pragma unroll
    for (int i = 0; i < 16; ++i) { oacc0[i] = 0.f; oacc1[i] = 0.f; }
    float la0 = 0.f, la1 = 0.f, la2 = 0.f, la3 = 0.f;

    // Prologue: 3 tiles in flight; wait Q + S0 + S1 (leave S2); QK(0) -> sA.
    prefetch(0, 0);
    prefetch(1, 1);
    prefetch(2, 2);
    asm volatile("s_waitcnt vmcnt(4)" ::: "memory");
    __builtin_amdgcn_s_barrier();
    __builtin_amdgcn_sched_barrier(0);

    auto qk_tile = [&](const char* kb, f32x16& d0, f32x16& d1) {
        #pragma unroll
        for (int i = 0; i < 16; ++i) { d0[i] = 0.f; d1[i] = 0.f; }
        __builtin_amdgcn_s_setprio(1);
        #pragma unroll
        for (int sd = 0; sd < 4; ++sd) {
            short8 k0 = *(const short8*)(kb + offA[sd]);
            short8 k1 = *(const short8*)(kb + offA[sd] + 4096);
            d0 = __builtin_amdgcn_mfma_f32_32x32x16_bf16(k0, aq[sd], d0, 0, 0, 0);
            d1 = __builtin_amdgcn_mfma_f32_32x32x16_bf16(k1, aq[sd], d1, 0, 0, 0);
        }
        __builtin_amdgcn_s_setprio(0);
    };

    f32x16 sA0, sA1, sB0, sB1;
    qk_tile((const char*)Ks, sA0, sA1);

    // Iteration kt: [QK(kt+1)->sN  ||  SM(kt) from sC] -> PV(kt) -> sync.
    auto tile_body = [&](f32x16& c0, f32x16& c1, f32x16& n0, f32x16& n1, int kt) {
        if (kt < 31)
            qk_tile((const char*)Ks + ((kt + 1) & 3) * 8192, n0, n1);

        // SM(kt): in-register softmax + P^T redistribution (independent of QK above).
        unsigned pw[4][4];   // pw[sk][word]: A-frag words for key-step sk (16 keys)
        #pragma unroll
        for (int half = 0; half < 2; ++half) {
            float p[8], q[8];
            #pragma unroll
            for (int jj = 0; jj < 8; ++jj) {
                p[jj] = __builtin_exp2f(c0[half * 8 + jj]);
                q[jj] = __builtin_exp2f(c1[half * 8 + jj]);
            }
            la0 += p[0] + p[4]; la1 += p[1] + p[5];
            la2 += p[2] + p[6]; la3 += p[3] + p[7];
            la0 += q[0] + q[4]; la1 += q[1] + q[5];
            la2 += q[2] + q[6]; la3 += q[3] + q[7];

            unsigned a0 = pack_bf16x2(p[0], p[1]), b0 = pack_bf16x2(p[2], p[3]);
            unsigned c0_ = pack_bf16x2(p[4], p[5]), d0_ = pack_bf16x2(p[6], p[7]);
            asm("v_permlane32_swap_b32 %0, %1" : "+v"(a0), "+v"(c0_));
            asm("v_permlane32_swap_b32 %0, %1" : "+v"(b0), "+v"(d0_));
            pw[half][0] = a0; pw[half][1] = b0; pw[half][2] = c0_; pw[half][3] = d0_;

            unsigned a1 = pack_bf16x2(q[0], q[1]), b1 = pack_bf16x2(q[2], q[3]);
            unsigned c1_ = pack_bf16x2(q[4], q[5]), d1_ = pack_bf16x2(q[6], q[7]);
            asm("v_permlane32_swap_b32 %0, %1" : "+v"(a1), "+v"(c1_));
            asm("v_permlane32_swap_b32 %0, %1" : "+v"(b1), "+v"(d1_));
            pw[2 + half][0] = a1; pw[2 + half][1] = b1; pw[2 + half][2] = c1_; pw[2 + half][3] = d1_;
        }

        // PV(kt): O[q][d] += P[q][keys] V[keys][d], two d-tiles of 32.
        const char* vb = (const char*)Vs + (kt & 3) * 8192;
        __builtin_amdgcn_s_setprio(1);
        #pragma unroll
        for (int sk = 0; sk < 4; ++sk) {
            union { unsigned u[4]; short8 s8; } pa;
            pa.u[0] = pw[sk][0]; pa.u[1] = pw[sk][1];
            pa.u[2] = pw[sk][2]; pa.u[3] = pw[sk][3];
            short8 v0 = *(const short8*)(vb + offA[sk]);
            short8 v1 = *(const short8*)(vb + offA[sk] + 4096);
            oacc0 = __builtin_amdgcn_mfma_f32_32x32x16_bf16(pa.s8, v0, oacc0, 0, 0, 0);
            oacc1 = __builtin_amdgcn_mfma_f32_32x32x16_bf16(pa.s8, v1, oacc1, 0, 0, 0);
        }
        __builtin_amdgcn_s_setprio(0);

        // Sync: stage distance 3; counted vmcnt (never 0 in steady state).
        if (kt <= 28) {
            prefetch(kt + 3, (kt + 3) & 3);
            asm volatile("s_waitcnt vmcnt(4)" ::: "memory");
            __builtin_amdgcn_s_barrier();
            __builtin_amdgcn_sched_barrier(0);
        } else if (kt == 29) {
            asm volatile("s_waitcnt vmcnt(0)" ::: "memory");
            __builtin_amdgcn_s_barrier();
            __builtin_amdgcn_sched_barrier(0);
        }
    };

    #pragma unroll 1
    for (int kt = 0; kt < 32; kt += 2) {
        tile_body(sA0, sA1, sB0, sB1, kt);
        tile_body(sB0, sB1, sA0, sA1, kt + 1);
    }

    // l[q=l31]: this lane has half the keys, the opposite 32-half has the rest.
    float l = (la0 + la1) + (la2 + la3);
    l += __shfl_xor(l, 32);
    const float inv = 1.0f / l;

    ushort_t* obase = Ob + (size_t)bh * S2 * DHEAD;
    #pragma unroll
    for (int r = 0; r < 16; ++r) {
        const int ql = (r & 3) + 8 * (r >> 2) + 4 * hi;   // q row of oacc reg r
        const float iv = __shfl(inv, ql);                  // l[q] lives at lane q (both halves)
        const size_t rowoff = (size_t)(r0 + 32 * w + ql) * DHEAD;
        obase[rowoff + l31]      = f2bf(oacc0[r] * iv);
        obase[rowoff + 32 + l31] = f2bf(oacc1[r] * iv);
    }
}

// ---------------------------------------------------------------------------
// Proj MFMA GEMM: out[4096,1024] (f32) = gather(O)[4096,1024] @ Wob^T + b_out.
// BM=128 x BN=64, grid (16,32)=512 blocks. Async staging double-buffered
// (one barrier per K-iter). Epilogue: LDS transpose -> f32x4 stores.
// ---------------------------------------------------------------------------
__global__ __launch_bounds__(256) void proj_gemm_mfma(
    const ushort_t* __restrict__ Ob, const ushort_t* __restrict__ Wob,
    const float* __restrict__ Bo, float* __restrict__ Out)
{
    __shared__ ushort_t As[2 * 128 * 32];   // 16 KB
    __shared__ ushort_t Bs[2 * 64 * 32];    // 8 KB
    __shared__ float    Sc[4][16 * 20];
    const int t = threadIdx.x;
    const int lane = t & 63, quad = lane >> 4, l15 = lane & 15;
    const int w = t >> 6;
    const int wm = (w >> 1) * 64, wn = (w & 1) * 32;
    const int r0 = blockIdx.y * 128, c0 = blockIdx.x * 64;
    const int branch = r0 >> 11, bb = (r0 & 2047) >> 10;

    const int g_chunk = (lane & 3) ^ ((lane >> 3) & 3);
    const int srow_lo = w * 16 + (lane >> 2);

    auto stage = [&](int k0, int buf) {
        int h = k0 >> 6, off = k0 & 63;
        const ushort_t* gpB = Wob + (size_t)(c0 + srow_lo) * HDIM + k0 + g_chunk * 8;
        ushort_t* lpB = Bs + buf * 2048 + w * 512;
        __builtin_amdgcn_global_load_lds(
            (const __attribute__((address_space(1))) void*)gpB,
            (__attribute__((address_space(3))) void*)lpB, 16, 0, 0);
        #pragma unroll
        for (int p = 0; p < 2; ++p) {
            int row = srow_lo + p * 64;
            int s = branch * NSEQ + (r0 & 1023) + row;
            const ushort_t* gpA = Ob + ((size_t)(bb * NHEADS + h) * S2 + s) * DHEAD + off + g_chunk * 8;
            ushort_t* lpA = As + buf * 4096 + p * 2048 + w * 512;
            __builtin_amdgcn_global_load_lds(
                (const __attribute__((address_space(1))) void*)gpA,
                (__attribute__((address_space(3))) void*)lpA, 16, 0, 0);
        }
    };

    f32x4 acc[4][2];
    #pragma unroll
    for (int i = 0; i < 4; ++i)
        #pragma unroll
        for (int j = 0; j < 2; ++j) acc[i][j] = (f32x4){0.f, 0.f, 0.f, 0.f};

    stage(0, 0);
    stage(32, 1);
    __syncthreads();

    const int sw = (l15 >> 1) & 3;
    for (int it = 0; it < 32; ++it) {
        const ushort_t* a = As + (it & 1) * 4096;
        const ushort_t* b = Bs + (it & 1) * 2048;
        short8 af[4], bf[2];
        #pragma unroll
        for (int mi = 0; mi < 4; ++mi) {
            int ra = wm + mi * 16 + l15;
            af[mi] = *(const short8*)(a + ra * 32 + ((quad ^ sw) * 8));
        }
        #pragma unroll
        for (int ni = 0; ni < 2; ++ni) {
            int rb = wn + ni * 16 + l15;
            bf[ni] = *(const short8*)(b + rb * 32 + ((quad ^ sw) * 8));
        }
        #pragma unroll
        for (int mi = 0; mi < 4; ++mi)
            #pragma unroll
            for (int ni = 0; ni < 2; ++ni)
                acc[mi][ni] = __builtin_amdgcn_mfma_f32_16x16x32_bf16(af[mi], bf[ni], acc[mi][ni], 0, 0, 0);
        __syncthreads();
        if (it < 30) stage((it + 2) * 32, it & 1);
    }

    float* sc = &Sc[w][0];
    const int row = lane >> 2, ch = lane & 3;
    #pragma unroll
    for (int mi = 0; mi < 4; ++mi) {
        int rb0 = r0 + wm + mi * 16;
        #pragma unroll
        for (int ni = 0; ni < 2; ++ni) {
            int cb = c0 + wn + ni * 16;
            #pragma unroll
            for (int reg = 0; reg < 4; ++reg)
                sc[(quad * 4 + reg) * 20 + l15] = acc[mi][ni][reg];
            float4 v = *(const float4*)&sc[row * 20 + ch * 4];
            float4 bias = *(const float4*)&Bo[cb + ch * 4];
            v.x += bias.x; v.y += bias.y; v.z += bias.z; v.w += bias.w;
            *(float4*)&Out[(size_t)(rb0 + row) * HDIM + cb + ch * 4] = v;
        }
    }
}

extern "C" void kernel_launch(void* const* d_in, const int* in_sizes, int n_in,
                              void* d_out, int out_size, void* d_ws, size_t ws_size,
                              hipStream_t stream) {
    const float* x    = (const float*)d_in[0];
    const float* x2   = (const float*)d_in[1];
    const float* wqkv = (const float*)d_in[2];
    const float* wout = (const float*)d_in[3];
    const float* bout = (const float*)d_in[4];
    float* out = (float*)d_out;

    // ws layout (bytes): Xb 8M | Wqb 6M | Wob 2M | Qb 8M | Kb 8M | Vtb 8M | Ob 8M = 48 MB
    char* ws = (char*)d_ws;
    ushort_t* Xb  = (ushort_t*)(ws);
    ushort_t* Wqb = (ushort_t*)(ws + (8u  << 20));
    ushort_t* Wob = (ushort_t*)(ws + (14u << 20));
    ushort_t* Qb  = (ushort_t*)(ws + (16u << 20));
    ushort_t* Kb  = (ushort_t*)(ws + (24u << 20));
    ushort_t* Vtb = (ushort_t*)(ws + (32u << 20));
    ushort_t* Ob  = (ushort_t*)(ws + (40u << 20));

    cvt_all<<<8192, 256, 0, stream>>>(x, x2, wqkv, wout, Xb, Wqb, Wob);
    qkv_gemm_mfma<<<dim3(24, 32), 256, 0, stream>>>(Xb, Wqb, Qb, Kb, Vtb);
    attn_mfma<<<512, 256, 0, stream>>>(Qb, Kb, Vtb, Ob);
    proj_gemm_mfma<<<dim3(16, 32), 256, 0, stream>>>(Ob, Wob, bout, out);
}